// Round 3
// baseline (419.028 us; speedup 1.0000x reference)
//
#include <hip/hip_runtime.h>

// RegressionInstancesModule on gfx950.
// R6: GEMM widened to full-N tile (208 px, 13 j-tiles), grid 128 blocks
// (m x oc-half). Block (m,0) = hs rows -> gap + fc fused in-block (no atomics,
// no gap HBM buffer). Block (m,1) = h1 rows -> LDS -> conv_c2 fused in-block
// (no Xh round-trip, convc2 kernel deleted). 4 -> 3 dispatches.
// R5 carried: lane=pixel ROI staging, prep+xb merged, K-step reg prefetch,
// nontemporal resize stores.

typedef unsigned short bfu;
typedef __attribute__((ext_vector_type(8))) short bf16x8;
typedef __attribute__((ext_vector_type(4))) float f32x4;

__device__ __forceinline__ float bf2f(bfu u) {
  union { unsigned int i; float f; } v;
  v.i = ((unsigned int)u) << 16;
  return v.f;
}
__device__ __forceinline__ bfu f2bf(float f) {
  union { float f; unsigned int i; } v;
  v.f = f;
  unsigned int u = v.i;
  u = (u + 0x7fffu + ((u >> 16) & 1u)) >> 16;
  return (bfu)u;
}

#define B_  4
#define N_  16
#define M_  64
#define H_  480
#define W_  640
#define HF  120
#define WF  160
#define C_  128
#define R_  14
#define PIX 196
#define NE  13
#define KK  1152   // 9*128

// workspace layout (float offsets)
#define WS_XB    0                         // bf16 Xb[64][196][128]
#define WS_C     1204224                   // f32 c[64][196]
#define WS_SCALE 1224960                   // f32 [64]
#define WS_SHIFT 1225024                   // f32 [64]
#define WS_WF    1225088                   // bf16 WF[13][192][1152], k=kidx*128+ic
#define WS_BIASF 2662784                   // f32 [13][192]
#define WS_W2    2665280                   // f32 [13][576], idx=kidx*64+ic
#define WS_B2    2672768                   // f32 [13] (pad 16)
#define WS_WFC   2672784                   // f32 [13][2][128]
#define WS_BFC   2676112                   // f32 [13][2] (pad 32)

#define XB_BLOCKS 256   // 4 blocks per instance, 32 channels each
#define PREP_BLOCKS 1024

// ---------------- merged: ROI-align staging (blocks 0..255) + weight prep ----------------
__global__ __launch_bounds__(256) void prep_xb_kernel(
    const float* __restrict__ fmap, const float* __restrict__ boxes,
    const float* __restrict__ w_s, const float* __restrict__ b_s,
    const float* __restrict__ w_fc, const float* __restrict__ b_fc,
    const float* __restrict__ w_c1, const float* __restrict__ b_c1,
    const float* __restrict__ w_c2, const float* __restrict__ b_c2,
    float* __restrict__ ws)
{
  int tid = threadIdx.x;
  if (blockIdx.x < XB_BLOCKS) {
    __shared__ int iy0[R_], ix0[R_];
    __shared__ float swy[R_], swx[R_];
    __shared__ unsigned int lt[PIX][17];   // packed bf16 pairs, padded stride
    int m  = blockIdx.x >> 2;
    int cb = (blockIdx.x & 3) * 32;        // channel base (32 channels)
    if (tid < 2*R_) {
      int r = tid % R_;
      bool isY = tid < R_;
      float b0 = boxes[m*4 + (isY ? 0 : 1)];
      float b2 = boxes[m*4 + (isY ? 2 : 3)];
      float lo = 0.6f * b0;
      float hi = lo + 0.1f + 0.3f * b2;
      float t = ((float)r + 0.5f) / (float)R_;
      float dim = isY ? (float)(HF-1) : (float)(WF-1);
      float s = (lo + (hi - lo) * t) * dim;
      int maxi = isY ? (HF-2) : (WF-2);
      int i0 = (int)floorf(s);
      i0 = i0 < 0 ? 0 : (i0 > maxi ? maxi : i0);
      float w = s - (float)i0;
      w = w < 0.f ? 0.f : (w > 1.f ? 1.f : w);
      if (isY) { iy0[r] = i0; swy[r] = w; } else { ix0[r] = i0; swx[r] = w; }
    }
    __syncthreads();
    int bi = m / N_;
    const float* fb = fmap + ((size_t)bi * C_ + cb) * HF * WF;
    if (tid < PIX) {
      int ry = tid / 14, rx = tid - (tid/14)*14;
      int y0 = iy0[ry], x0 = ix0[rx];
      float wy = swy[ry], wx = swx[rx];
      float w00 = (1.f-wy)*(1.f-wx), w01 = (1.f-wy)*wx;
      float w10 = wy*(1.f-wx),       w11 = wy*wx;
      const float* fp = fb + (size_t)y0*WF + x0;
      #pragma unroll 4
      for (int c2 = 0; c2 < 16; ++c2) {
        const float* f0 = fp + (size_t)(2*c2)*HF*WF;
        const float* f1 = f0 + (size_t)HF*WF;
        float v0 = f0[0]*w00 + f0[1]*w01 + f0[WF]*w10 + f0[WF+1]*w11;
        float v1 = f1[0]*w00 + f1[1]*w01 + f1[WF]*w10 + f1[WF+1]*w11;
        lt[tid][c2] = (unsigned int)f2bf(v0) | ((unsigned int)f2bf(v1) << 16);
      }
    }
    __syncthreads();
    unsigned int* xbw = (unsigned int*)(ws + WS_XB);
    for (int idx = tid; idx < PIX*16; idx += 256) {
      int p = idx >> 4, c2 = idx & 15;
      xbw[((size_t)m*PIX + p)*64 + (cb >> 1) + c2] = lt[p][c2];
    }
    return;
  }

  // ---- weight prep (blocks 256..1279), grid-stride ----
  const int P0 = NE*192*KK;     // WF bf16
  const int P1 = NE*192;        // biasf
  const int P2 = NE*576;        // w2
  const int P3 = NE;            // b2
  const int P4 = NE*256;        // wfc
  const int P5 = NE*2;          // bfc
  int total = P0+P1+P2+P3+P4+P5;
  bfu* wf = (bfu*)(ws + WS_WF);
  for (int idx = (blockIdx.x - XB_BLOCKS)*256 + tid; idx < total;
       idx += PREP_BLOCKS*256) {
    int d = idx;
    if (d < P0) {
      int e = d / (192*KK);
      int r = d - e*(192*KK);
      int oc = r / KK;
      int k  = r - oc*KK;
      int kidx = k >> 7, ic = k & 127;
      float v = (oc < 128) ? w_s[((e*128 + oc)*128 + ic)*9 + kidx]
                           : w_c1[((e*64 + (oc-128))*128 + ic)*9 + kidx];
      wf[d] = f2bf(v);
      continue;
    }
    d -= P0;
    if (d < P1) {
      int e = d / 192, oc = d - e*192;
      ws[WS_BIASF + d] = (oc < 128) ? b_s[e*128 + oc] : b_c1[e*64 + oc - 128];
      continue;
    }
    d -= P1;
    if (d < P2) {
      int e = d / 576, k = d - e*576;
      int kidx = k >> 6, ic = k & 63;
      ws[WS_W2 + d] = w_c2[(e*64 + ic)*9 + kidx];
      continue;
    }
    d -= P2;
    if (d < P3) { ws[WS_B2 + d] = b_c2[d]; continue; }
    d -= P3;
    if (d < P4) { ws[WS_WFC + d] = w_fc[d]; continue; }
    d -= P4;
    if (d < P5) { ws[WS_BFC + d] = b_fc[d]; }
  }
}

// ---------------- fused GEMM, full-N tile: [128oc x 208pix] per block ----------------
// grid = 64 m * 2 mb. 4 waves, wave w owns rows w*32..w*32+31, all 208 cols.
// mb=0: hs rows 0..127 -> gap (LDS) -> fc -> scale/shift.
// mb=1: h1 rows 128..191 -> relu bf16 -> LDS -> conv_c2 -> ws_C.
__global__ __launch_bounds__(256) void gemm_kernel(
    const int* __restrict__ labels, float* __restrict__ ws,
    float* __restrict__ out)
{
  __shared__ __align__(16) char smem[28672];
  bfu* lA = (bfu*)smem;             // [128][32] shorts (8 KB)
  bfu* lB = (bfu*)(smem + 8192);    // [208][32] shorts (13 KB)

  const bfu* Xb  = (const bfu*)(ws + WS_XB);
  const bfu* WFp = (const bfu*)(ws + WS_WF);
  const float* biasf = ws + WS_BIASF;

  int bx = blockIdx.x;
  int m  = bx >> 1;
  int mb = bx & 1;
  int e = labels[m];
  int tid = threadIdx.x;
  int wave = tid >> 6, lane = tid & 63;
  int l15 = lane & 15, q = lane >> 4;

  // A staging: units u = tid, tid+256; row=u>>2, kc=u&3
  int arow0 = tid >> 2, arow1 = arow0 + 64;
  int kc = tid & 3;
  int aoff0 = arow0*32 + (kc ^ ((arow0 >> 1) & 3))*8;
  int aoff1 = arow1*32 + (kc ^ ((arow1 >> 1) & 3))*8;
  int g0 = mb*128 + arow0, g1 = mb*128 + arow1;
  bool av0 = g0 < 192, av1 = g1 < 192;
  const bfu* wfe = WFp + (size_t)e*192*KK;
  const bfu* wr0 = wfe + (size_t)g0*KK + kc*8;
  const bfu* wr1 = wfe + (size_t)g1*KK + kc*8;

  // B staging: 832 units (208 rows x 4 kc); thread handles u = tid + 256*k2
  int bpy[4], bpx[4], boff[4];
  bool bu[4], bva[4];
  #pragma unroll
  for (int k2 = 0; k2 < 4; ++k2) {
    int u = tid + 256*k2;
    int r = u >> 2;
    bu[k2]  = (u < 832);
    bva[k2] = bu[k2] && (r < PIX);
    int py = r / 14;
    bpy[k2] = py; bpx[k2] = r - py*14;
    boff[k2] = r*32 + (kc ^ ((r >> 1) & 3))*8;
  }
  const bfu* xbm = Xb + (size_t)m*PIX*128;

  f32x4 acc[2][13];
  #pragma unroll
  for (int i = 0; i < 2; ++i)
    #pragma unroll
    for (int j = 0; j < 13; ++j)
      acc[i][j] = (f32x4){0.f, 0.f, 0.f, 0.f};

  const uint4 z4 = make_uint4(0,0,0,0);
  uint4 pa0, pa1, pb[4];
  auto issue = [&](int s) {
    int kidx = s >> 2, icc = s & 3;
    int t3 = kidx / 3;
    int dy = t3 - 1, dx = (kidx - t3*3) - 1;
    pa0 = av0 ? *(const uint4*)(wr0 + s*32) : z4;
    pa1 = av1 ? *(const uint4*)(wr1 + s*32) : z4;
    #pragma unroll
    for (int k2 = 0; k2 < 4; ++k2) {
      int ys = bpy[k2] + dy, xs = bpx[k2] + dx;
      bool v = bva[k2] && (unsigned)ys < 14u && (unsigned)xs < 14u;
      pb[k2] = v ? *(const uint4*)(xbm + (size_t)(ys*14+xs)*128 + icc*32 + kc*8) : z4;
    }
  };
  issue(0);

  for (int s = 0; s < 36; ++s) {
    __syncthreads();
    *(uint4*)&lA[aoff0] = pa0;
    *(uint4*)&lA[aoff1] = pa1;
    #pragma unroll
    for (int k2 = 0; k2 < 4; ++k2)
      if (bu[k2]) *(uint4*)&lB[boff[k2]] = pb[k2];
    __syncthreads();
    if (s < 35) issue(s+1);
    int ra0 = wave*32 + l15, ra1 = ra0 + 16;
    bf16x8 af0 = *(const bf16x8*)&lA[ra0*32 + (q ^ ((ra0 >> 1) & 3))*8];
    bf16x8 af1 = *(const bf16x8*)&lA[ra1*32 + (q ^ ((ra1 >> 1) & 3))*8];
    #pragma unroll
    for (int j = 0; j < 13; ++j) {
      int rb = j*16 + l15;
      bf16x8 bfv = *(const bf16x8*)&lB[rb*32 + (q ^ ((rb >> 1) & 3))*8];
      acc[0][j] = __builtin_amdgcn_mfma_f32_16x16x32_bf16(af0, bfv, acc[0][j], 0, 0, 0);
      acc[1][j] = __builtin_amdgcn_mfma_f32_16x16x32_bf16(af1, bfv, acc[1][j], 0, 0, 0);
    }
  }

  __syncthreads();   // lA/lB dead; smem reused below

  if (mb == 0) {
    // ---- gap (LDS) + fc ----
    float* gapL = (float*)(smem + 25088);  // [128]
    #pragma unroll
    for (int i = 0; i < 2; ++i) {
      int ocb = wave*32 + i*16 + q*4;
      f32x4 bv4 = *(const f32x4*)&biasf[e*192 + ocb];
      #pragma unroll
      for (int r = 0; r < 4; ++r) {
        float sum = 0.f;
        #pragma unroll
        for (int j = 0; j < 13; ++j) {
          int p = j*16 + l15;
          float v = acc[i][j][r] + bv4[r];
          v = v > 0.f ? v : 0.f;
          if (p < PIX) sum += v;
        }
        sum += __shfl_xor(sum, 1);
        sum += __shfl_xor(sum, 2);
        sum += __shfl_xor(sum, 4);
        sum += __shfl_xor(sum, 8);
        if (l15 == 0) gapL[ocb + r] = sum;
      }
    }
    __syncthreads();
    if (wave < 2) {
      const float* wv = ws + WS_WFC + (e*2 + wave)*C_;
      float s = gapL[lane]*wv[lane] + gapL[lane+64]*wv[lane+64];
      #pragma unroll
      for (int d = 32; d; d >>= 1) s += __shfl_xor(s, d);
      if (lane == 0) {
        s = ws[WS_BFC + e*2 + wave] + s * (1.f/(float)PIX);
        size_t base = (size_t)2 * M_ * H_ * W_;
        if (wave == 0) { ws[WS_SCALE + m] = s; out[base + m] = s; }
        else           { ws[WS_SHIFT + m] = s; out[base + M_ + m] = s; }
      }
    }
  } else {
    // ---- h1 -> LDS (bf16) -> conv_c2 ----
    bfu* xh = (bfu*)smem;                  // [196][64]  (25088 B)
    float* w2l = (float*)(smem + 25088);   // [576]
    for (int i2 = tid; i2 < 576; i2 += 256)
      w2l[i2] = ws[WS_W2 + e*576 + i2];
    if (wave < 2) {
      #pragma unroll
      for (int i = 0; i < 2; ++i) {
        int icb = wave*32 + i*16 + q*4;
        f32x4 bv4 = *(const f32x4*)&biasf[e*192 + 128 + icb];
        #pragma unroll
        for (int j = 0; j < 13; ++j) {
          int p = j*16 + l15;
          if (p < PIX) {
            ushort4 pk;
            float v0 = acc[i][j][0] + bv4[0]; v0 = v0 > 0.f ? v0 : 0.f;
            float v1 = acc[i][j][1] + bv4[1]; v1 = v1 > 0.f ? v1 : 0.f;
            float v2 = acc[i][j][2] + bv4[2]; v2 = v2 > 0.f ? v2 : 0.f;
            float v3 = acc[i][j][3] + bv4[3]; v3 = v3 > 0.f ? v3 : 0.f;
            pk.x = f2bf(v0); pk.y = f2bf(v1); pk.z = f2bf(v2); pk.w = f2bf(v3);
            *(ushort4*)&xh[p*64 + icb] = pk;
          }
        }
      }
    }
    __syncthreads();
    if (tid < PIX) {
      int y = tid / 14, x = tid - (tid/14)*14;
      float cacc = 0.f;
      #pragma unroll
      for (int kidx = 0; kidx < 9; ++kidx) {
        int ys = y + kidx/3 - 1, xs = x + (kidx - (kidx/3)*3) - 1;
        if ((unsigned)ys < 14u && (unsigned)xs < 14u) {
          const bfu* xr = xh + (ys*14 + xs)*64;
          const float* wr = w2l + kidx*64;
          #pragma unroll
          for (int cc = 0; cc < 8; ++cc) {
            bf16x8 xv = *(const bf16x8*)&xr[cc*8];
            f32x4 wa = *(const f32x4*)&wr[cc*8];
            f32x4 wb = *(const f32x4*)&wr[cc*8 + 4];
            cacc += bf2f((bfu)xv[0])*wa[0] + bf2f((bfu)xv[1])*wa[1]
                  + bf2f((bfu)xv[2])*wa[2] + bf2f((bfu)xv[3])*wa[3]
                  + bf2f((bfu)xv[4])*wb[0] + bf2f((bfu)xv[5])*wb[1]
                  + bf2f((bfu)xv[6])*wb[2] + bf2f((bfu)xv[7])*wb[3];
          }
        }
      }
      ws[WS_C + m*PIX + tid] = cacc + ws[WS_B2 + e];
    }
  }
}

// ---------------- bilinear resize 14x14 -> 480x640 + affine ----------------
__global__ __launch_bounds__(256) void resize_kernel(
    const float* __restrict__ ws_c, const float* __restrict__ ws_scale,
    const float* __restrict__ ws_shift, float* __restrict__ out)
{
  __shared__ float cs[PIX];
  int bx = blockIdx.x;
  int m = bx / 150;
  int chunk = bx % 150;
  int tid = threadIdx.x;
  if (tid < PIX) cs[tid] = ws_c[m*PIX + tid];
  __syncthreads();
  float sc = ws_scale[m], sh = ws_shift[m];
  int q0 = chunk*2048 + tid*8;
  int y = q0 / W_;
  int x0i = q0 - y*W_;
  float py = ((float)y + 0.5f) * (14.f/(float)H_) - 0.5f;
  py = fminf(fmaxf(py, 0.f), 13.f);
  int y0 = (int)py; y0 = y0 > 12 ? 12 : y0;
  float wy = py - (float)y0;
  const float* r0 = cs + y0*R_;
  const float* r1 = r0 + R_;
  float vd[8], vc[8];
  #pragma unroll
  for (int u = 0; u < 8; ++u) {
    int x = x0i + u;
    float px = ((float)x + 0.5f) * (14.f/(float)W_) - 0.5f;
    px = fminf(fmaxf(px, 0.f), 13.f);
    int xq = (int)px; xq = xq > 12 ? 12 : xq;
    float wx = px - (float)xq;
    float v = (r0[xq]*(1.f-wx) + r0[xq+1]*wx) * (1.f-wy)
            + (r1[xq]*(1.f-wx) + r1[xq+1]*wx) * wy;
    vc[u] = v;
    vd[u] = fmaxf(v*sc + sh, 0.001f);
  }
  size_t base = (size_t)m * H_ * W_ + q0;
  float* od = out + base;
  float* oc = out + (size_t)M_*H_*W_ + base;
  f32x4 d0 = (f32x4){vd[0], vd[1], vd[2], vd[3]};
  f32x4 d1 = (f32x4){vd[4], vd[5], vd[6], vd[7]};
  f32x4 c0 = (f32x4){vc[0], vc[1], vc[2], vc[3]};
  f32x4 c1 = (f32x4){vc[4], vc[5], vc[6], vc[7]};
  __builtin_nontemporal_store(d0, (f32x4*)(od));
  __builtin_nontemporal_store(d1, (f32x4*)(od + 4));
  __builtin_nontemporal_store(c0, (f32x4*)(oc));
  __builtin_nontemporal_store(c1, (f32x4*)(oc + 4));
}

extern "C" void kernel_launch(void* const* d_in, const int* in_sizes, int n_in,
                              void* d_out, int out_size, void* d_ws, size_t ws_size,
                              hipStream_t stream) {
  const float* fmap  = (const float*)d_in[2];
  const float* boxes = (const float*)d_in[8];
  const int* labels  = (const int*)d_in[9];
  const float* w_s  = (const float*)d_in[10];
  const float* b_s  = (const float*)d_in[11];
  const float* w_fc = (const float*)d_in[12];
  const float* b_fc = (const float*)d_in[13];
  const float* w_c1 = (const float*)d_in[14];
  const float* b_c1 = (const float*)d_in[15];
  const float* w_c2 = (const float*)d_in[16];
  const float* b_c2 = (const float*)d_in[17];
  float* ws = (float*)d_ws;
  float* out = (float*)d_out;

  hipLaunchKernelGGL(prep_xb_kernel, dim3(XB_BLOCKS + PREP_BLOCKS), dim3(256), 0, stream,
                     fmap, boxes, w_s, b_s, w_fc, b_fc, w_c1, b_c1, w_c2, b_c2, ws);
  hipLaunchKernelGGL(gemm_kernel, dim3(M_*2), dim3(256), 0, stream,
                     labels, ws, out);
  hipLaunchKernelGGL(resize_kernel, dim3(M_*150), dim3(256), 0, stream,
                     ws + WS_C, ws + WS_SCALE, ws + WS_SHIFT, out);
}

// Round 4
// 382.442 us; speedup vs baseline: 1.0957x; 1.0957x over previous
//
#include <hip/hip_runtime.h>

// RegressionInstancesModule on gfx950.
// R7 = R5 structure (proven 376.8us) + convc2/fc folded into resize.
// R6's full-N GEMM regressed 42us: grid 128 blocks left half the CUs idle and
// VGPR ~170 capped occupancy. Reverted. Instead each resize block recomputes
// its <=3 needed c-rows (conv_c2 over <=5 Xh rows from L2) + fc from gap sums:
// deletes the convc2 dispatch, its gap, and the ws_C round-trip with ~5us of
// redundant, fully-parallel compute. 3 dispatches total.

typedef unsigned short bfu;
typedef __attribute__((ext_vector_type(8))) short bf16x8;
typedef __attribute__((ext_vector_type(4))) float f32x4;

__device__ __forceinline__ float bf2f(bfu u) {
  union { unsigned int i; float f; } v;
  v.i = ((unsigned int)u) << 16;
  return v.f;
}
__device__ __forceinline__ bfu f2bf(float f) {
  union { float f; unsigned int i; } v;
  v.f = f;
  unsigned int u = v.i;
  u = (u + 0x7fffu + ((u >> 16) & 1u)) >> 16;
  return (bfu)u;
}

#define B_  4
#define N_  16
#define M_  64
#define H_  480
#define W_  640
#define HF  120
#define WF  160
#define C_  128
#define R_  14
#define PIX 196
#define NE  13
#define KK  1152   // 9*128

// workspace layout (float offsets)
#define WS_XB    0                         // bf16 Xb[64][196][128]
#define WS_XH    802816                    // bf16 Xh[64][196][64]
#define WS_GAP   1216768                   // f32 gap[64][128] (sums; zeroed)
#define WS_WF    1225088                   // bf16 WF[13][192][1152], k=kidx*128+ic
#define WS_BIASF 2662784                   // f32 [13][192]
#define WS_W2    2665280                   // f32 [13][576], idx=kidx*64+ic
#define WS_B2    2672768                   // f32 [13] (pad 16)
#define WS_WFC   2672784                   // f32 [13][2][128]
#define WS_BFC   2676112                   // f32 [13][2] (pad 32)

#define XB_BLOCKS 256   // 4 blocks per instance, 32 channels each
#define PREP_BLOCKS 1024

// ---------------- merged: ROI-align staging (blocks 0..255) + weight prep ----------------
__global__ __launch_bounds__(256) void prep_xb_kernel(
    const float* __restrict__ fmap, const float* __restrict__ boxes,
    const float* __restrict__ w_s, const float* __restrict__ b_s,
    const float* __restrict__ w_fc, const float* __restrict__ b_fc,
    const float* __restrict__ w_c1, const float* __restrict__ b_c1,
    const float* __restrict__ w_c2, const float* __restrict__ b_c2,
    float* __restrict__ ws)
{
  int tid = threadIdx.x;
  if (blockIdx.x < XB_BLOCKS) {
    __shared__ int iy0[R_], ix0[R_];
    __shared__ float swy[R_], swx[R_];
    __shared__ unsigned int lt[PIX][17];   // packed bf16 pairs, padded stride
    int m  = blockIdx.x >> 2;
    int cb = (blockIdx.x & 3) * 32;        // channel base (32 channels)
    if (tid < 2*R_) {
      int r = tid % R_;
      bool isY = tid < R_;
      float b0 = boxes[m*4 + (isY ? 0 : 1)];
      float b2 = boxes[m*4 + (isY ? 2 : 3)];
      float lo = 0.6f * b0;
      float hi = lo + 0.1f + 0.3f * b2;
      float t = ((float)r + 0.5f) / (float)R_;
      float dim = isY ? (float)(HF-1) : (float)(WF-1);
      float s = (lo + (hi - lo) * t) * dim;
      int maxi = isY ? (HF-2) : (WF-2);
      int i0 = (int)floorf(s);
      i0 = i0 < 0 ? 0 : (i0 > maxi ? maxi : i0);
      float w = s - (float)i0;
      w = w < 0.f ? 0.f : (w > 1.f ? 1.f : w);
      if (isY) { iy0[r] = i0; swy[r] = w; } else { ix0[r] = i0; swx[r] = w; }
    }
    __syncthreads();
    int bi = m / N_;
    const float* fb = fmap + ((size_t)bi * C_ + cb) * HF * WF;
    if (tid < PIX) {
      int ry = tid / 14, rx = tid - (tid/14)*14;
      int y0 = iy0[ry], x0 = ix0[rx];
      float wy = swy[ry], wx = swx[rx];
      float w00 = (1.f-wy)*(1.f-wx), w01 = (1.f-wy)*wx;
      float w10 = wy*(1.f-wx),       w11 = wy*wx;
      const float* fp = fb + (size_t)y0*WF + x0;
      #pragma unroll 4
      for (int c2 = 0; c2 < 16; ++c2) {
        const float* f0 = fp + (size_t)(2*c2)*HF*WF;
        const float* f1 = f0 + (size_t)HF*WF;
        float v0 = f0[0]*w00 + f0[1]*w01 + f0[WF]*w10 + f0[WF+1]*w11;
        float v1 = f1[0]*w00 + f1[1]*w01 + f1[WF]*w10 + f1[WF+1]*w11;
        lt[tid][c2] = (unsigned int)f2bf(v0) | ((unsigned int)f2bf(v1) << 16);
      }
    }
    __syncthreads();
    unsigned int* xbw = (unsigned int*)(ws + WS_XB);
    for (int idx = tid; idx < PIX*16; idx += 256) {
      int p = idx >> 4, c2 = idx & 15;
      xbw[((size_t)m*PIX + p)*64 + (cb >> 1) + c2] = lt[p][c2];
    }
    return;
  }

  // ---- weight prep (blocks 256..1279), grid-stride ----
  const int P0 = NE*192*KK;     // WF bf16
  const int P1 = NE*192;        // biasf
  const int P2 = NE*576;        // w2
  const int P3 = NE;            // b2
  const int P4 = NE*256;        // wfc
  const int P5 = NE*2;          // bfc
  const int P6 = M_*C_;         // gap zero
  int total = P0+P1+P2+P3+P4+P5+P6;
  bfu* wf = (bfu*)(ws + WS_WF);
  for (int idx = (blockIdx.x - XB_BLOCKS)*256 + tid; idx < total;
       idx += PREP_BLOCKS*256) {
    int d = idx;
    if (d < P0) {
      int e = d / (192*KK);
      int r = d - e*(192*KK);
      int oc = r / KK;
      int k  = r - oc*KK;
      int kidx = k >> 7, ic = k & 127;
      float v = (oc < 128) ? w_s[((e*128 + oc)*128 + ic)*9 + kidx]
                           : w_c1[((e*64 + (oc-128))*128 + ic)*9 + kidx];
      wf[d] = f2bf(v);
      continue;
    }
    d -= P0;
    if (d < P1) {
      int e = d / 192, oc = d - e*192;
      ws[WS_BIASF + d] = (oc < 128) ? b_s[e*128 + oc] : b_c1[e*64 + oc - 128];
      continue;
    }
    d -= P1;
    if (d < P2) {
      int e = d / 576, k = d - e*576;
      int kidx = k >> 6, ic = k & 63;
      ws[WS_W2 + d] = w_c2[(e*64 + ic)*9 + kidx];
      continue;
    }
    d -= P2;
    if (d < P3) { ws[WS_B2 + d] = b_c2[d]; continue; }
    d -= P3;
    if (d < P4) { ws[WS_WFC + d] = w_fc[d]; continue; }
    d -= P4;
    if (d < P5) { ws[WS_BFC + d] = b_fc[d]; continue; }
    d -= P5;
    ws[WS_GAP + d] = 0.f;
  }
}

// ---------------- fused GEMM: [192oc x 208pix] = WF x im2col(Xb) ----------------
// R5 structure: 256 blocks (m x mb x nb), 128x128 tile, 36 K-steps, reg prefetch.
__global__ __launch_bounds__(256) void gemm_kernel(
    const int* __restrict__ labels, float* __restrict__ ws)
{
  __shared__ bfu lA[128*32];
  __shared__ bfu lB[128*32];
  const bfu* Xb = (const bfu*)(ws + WS_XB);
  const bfu* WFp = (const bfu*)(ws + WS_WF);
  const float* biasf = ws + WS_BIASF;
  float* gap = ws + WS_GAP;
  bfu* Xh = (bfu*)(ws + WS_XH);

  int bx = blockIdx.x;
  int m  = bx >> 2;
  int mb = (bx >> 1) & 1;
  int nb = bx & 1;
  int e = labels[m];
  int tid = threadIdx.x;
  int wave = tid >> 6, lane = tid & 63;
  int wm = wave >> 1, wn = wave & 1;
  int l15 = lane & 15, q = lane >> 4;

  int row0 = tid >> 2, row1 = row0 + 64;
  int kc = tid & 3;
  int loff0 = row0*32 + (kc ^ ((row0 >> 1) & 3))*8;
  int loff1 = row1*32 + (kc ^ ((row1 >> 1) & 3))*8;
  int g0 = mb*128 + row0, g1 = mb*128 + row1;
  bool av0 = g0 < 192, av1 = g1 < 192;
  const bfu* wfe = WFp + (size_t)e*192*KK;
  const bfu* wr0 = wfe + (size_t)g0*KK + kc*8;
  const bfu* wr1 = wfe + (size_t)g1*KK + kc*8;
  int pg0 = nb*128 + row0, pg1 = nb*128 + row1;
  int py0 = pg0 / 14, px0 = pg0 - (pg0/14)*14;
  int py1 = pg1 / 14, px1 = pg1 - (pg1/14)*14;
  bool pv0 = pg0 < PIX, pv1 = pg1 < PIX;
  const bfu* xbm = Xb + (size_t)m*PIX*128;

  f32x4 acc[4][4];
  #pragma unroll
  for (int i = 0; i < 4; ++i)
    #pragma unroll
    for (int j = 0; j < 4; ++j)
      acc[i][j] = (f32x4){0.f, 0.f, 0.f, 0.f};

  const uint4 z4 = make_uint4(0,0,0,0);
  uint4 na0, na1, nb0, nb1;
  auto issue = [&](int s, uint4& A0, uint4& A1, uint4& B0, uint4& B1) {
    int kidx = s >> 2, icc = s & 3;
    int t3 = kidx / 3;
    int dy = t3 - 1, dx = (kidx - t3*3) - 1;
    A0 = av0 ? *(const uint4*)(wr0 + s*32) : z4;
    A1 = av1 ? *(const uint4*)(wr1 + s*32) : z4;
    int ys0 = py0 + dy, xs0 = px0 + dx;
    int ys1 = py1 + dy, xs1 = px1 + dx;
    bool v0 = pv0 && (unsigned)ys0 < 14u && (unsigned)xs0 < 14u;
    bool v1 = pv1 && (unsigned)ys1 < 14u && (unsigned)xs1 < 14u;
    B0 = v0 ? *(const uint4*)(xbm + (size_t)(ys0*14+xs0)*128 + icc*32 + kc*8) : z4;
    B1 = v1 ? *(const uint4*)(xbm + (size_t)(ys1*14+xs1)*128 + icc*32 + kc*8) : z4;
  };
  issue(0, na0, na1, nb0, nb1);

  for (int s = 0; s < 36; ++s) {
    __syncthreads();
    *(uint4*)&lA[loff0] = na0;
    *(uint4*)&lA[loff1] = na1;
    *(uint4*)&lB[loff0] = nb0;
    *(uint4*)&lB[loff1] = nb1;
    __syncthreads();
    if (s < 35) issue(s+1, na0, na1, nb0, nb1);
    bf16x8 af[4], bfr[4];
    #pragma unroll
    for (int i = 0; i < 4; ++i) {
      int r = wm*64 + i*16 + l15;
      af[i] = *(const bf16x8*)&lA[r*32 + (q ^ ((r >> 1) & 3))*8];
    }
    #pragma unroll
    for (int j = 0; j < 4; ++j) {
      int r = wn*64 + j*16 + l15;
      bfr[j] = *(const bf16x8*)&lB[r*32 + (q ^ ((r >> 1) & 3))*8];
    }
    #pragma unroll
    for (int i = 0; i < 4; ++i)
      #pragma unroll
      for (int j = 0; j < 4; ++j)
        acc[i][j] = __builtin_amdgcn_mfma_f32_16x16x32_bf16(af[i], bfr[j], acc[i][j], 0, 0, 0);
  }

  if (mb == 0) {
    #pragma unroll
    for (int i = 0; i < 4; ++i) {
      int ocb = wm*64 + i*16 + q*4;
      f32x4 bv = *(const f32x4*)&biasf[e*192 + ocb];
      #pragma unroll
      for (int r = 0; r < 4; ++r) {
        float sum = 0.f;
        #pragma unroll
        for (int j = 0; j < 4; ++j) {
          int p = nb*128 + wn*64 + j*16 + l15;
          float v = acc[i][j][r] + bv[r];
          v = v > 0.f ? v : 0.f;
          if (p < PIX) sum += v;
        }
        sum += __shfl_xor(sum, 1);
        sum += __shfl_xor(sum, 2);
        sum += __shfl_xor(sum, 4);
        sum += __shfl_xor(sum, 8);
        if (l15 == 0) atomicAdd(&gap[m*C_ + ocb + r], sum);
      }
    }
  } else if (wm == 0) {
    #pragma unroll
    for (int i = 0; i < 4; ++i) {
      int icb = i*16 + q*4;
      f32x4 bv = *(const f32x4*)&biasf[e*192 + 128 + icb];
      #pragma unroll
      for (int j = 0; j < 4; ++j) {
        int p = nb*128 + wn*64 + j*16 + l15;
        if (p < PIX) {
          ushort4 pk;
          float v0 = acc[i][j][0] + bv[0]; v0 = v0 > 0.f ? v0 : 0.f;
          float v1 = acc[i][j][1] + bv[1]; v1 = v1 > 0.f ? v1 : 0.f;
          float v2 = acc[i][j][2] + bv[2]; v2 = v2 > 0.f ? v2 : 0.f;
          float v3 = acc[i][j][3] + bv[3]; v3 = v3 > 0.f ? v3 : 0.f;
          pk.x = f2bf(v0); pk.y = f2bf(v1); pk.z = f2bf(v2); pk.w = f2bf(v3);
          *(ushort4*)&Xh[((size_t)m*PIX + p)*64 + icb] = pk;
        }
      }
    }
  }
}

// ---------------- resize + in-block conv_c2 + fc ----------------
// Each block covers 2048 contiguous output px (<=4 output rows -> <=3 source
// c-rows). Loads the <=5 needed Xh rows (9KB, L2-resident), computes its own
// c rows + scale/shift, then bilinear+affine with NT stores.
__global__ __launch_bounds__(256) void resize_kernel(
    const int* __restrict__ labels, const float* __restrict__ ws,
    float* __restrict__ out)
{
  __shared__ bfu xh[5*14*64];    // Xh rows XR0..XR0+4
  __shared__ float w2l[576];
  __shared__ float cs[3*14];     // c rows Y0..Y0+2
  __shared__ float ssh[2];
  int bx = blockIdx.x;
  int m = bx / 150;
  int chunk = bx - m*150;
  int e = labels[m];
  int tid = threadIdx.x;
  int wave = tid >> 6, lane = tid & 63;

  auto srcy = [](int y)->float {
    float py = ((float)y + 0.5f) * (14.f/(float)H_) - 0.5f;
    return fminf(fmaxf(py, 0.f), 13.f);
  };
  int q0 = chunk*2048;
  int yo0 = q0 / W_;
  int yo1 = (q0 + 2047) / W_;
  int Y0 = (int)srcy(yo0); Y0 = Y0 > 12 ? 12 : Y0;
  int Yb = (int)srcy(yo1); Yb = Yb > 12 ? 12 : Yb;
  int XR0 = Y0 - 1;

  // stage Xh rows XR0..XR0+4 (560 uint4 units, zero OOB rows)
  const bfu* XhG = (const bfu*)(ws + WS_XH) + (size_t)m*PIX*64;
  const uint4 z4 = make_uint4(0,0,0,0);
  for (int i = tid; i < 560; i += 256) {
    int slot = i / 112, rem = i - slot*112;
    int r = XR0 + slot;
    uint4 v = z4;
    if ((unsigned)r < 14u)
      v = *(const uint4*)(XhG + (size_t)r*896 + rem*8);
    *(uint4*)&xh[slot*896 + rem*8] = v;
  }
  for (int i = tid; i < 576; i += 256)
    w2l[i] = ws[WS_W2 + e*576 + i];

  // fc: wave0 -> scale, wave1 -> shift
  if (wave < 2) {
    const float* g  = ws + WS_GAP + m*C_;
    const float* wv = ws + WS_WFC + (e*2 + wave)*C_;
    float s = g[lane]*wv[lane] + g[lane+64]*wv[lane+64];
    #pragma unroll
    for (int d = 32; d; d >>= 1) s += __shfl_xor(s, d);
    if (lane == 0) {
      s = ws[WS_BFC + e*2 + wave] + s * (1.f/(float)PIX);
      ssh[wave] = s;
      if (chunk == 0) {
        size_t base = (size_t)2 * M_ * H_ * W_;
        out[base + wave*M_ + m] = s;
      }
    }
  }
  __syncthreads();

  // conv_c2 for rows Y0..Y0+2 (42 threads, 1 px each)
  if (tid < 42) {
    int rr = tid / 14, x = tid - rr*14;
    int ys = Y0 + rr;
    if (ys <= 13) {
      float cacc = 0.f;
      #pragma unroll
      for (int kidx = 0; kidx < 9; ++kidx) {
        int ysrc = ys + kidx/3 - 1, xsrc = x + (kidx - (kidx/3)*3) - 1;
        if ((unsigned)ysrc < 14u && (unsigned)xsrc < 14u) {
          const bfu* xr = xh + ((ysrc - XR0)*14 + xsrc)*64;
          const float* wr = w2l + kidx*64;
          #pragma unroll
          for (int cc = 0; cc < 8; ++cc) {
            bf16x8 xv = *(const bf16x8*)&xr[cc*8];
            f32x4 wa = *(const f32x4*)&wr[cc*8];
            f32x4 wb = *(const f32x4*)&wr[cc*8 + 4];
            cacc += bf2f((bfu)xv[0])*wa[0] + bf2f((bfu)xv[1])*wa[1]
                  + bf2f((bfu)xv[2])*wa[2] + bf2f((bfu)xv[3])*wa[3]
                  + bf2f((bfu)xv[4])*wb[0] + bf2f((bfu)xv[5])*wb[1]
                  + bf2f((bfu)xv[6])*wb[2] + bf2f((bfu)xv[7])*wb[3];
          }
        }
      }
      cs[tid] = cacc + ws[WS_B2 + e];
    }
  }
  __syncthreads();

  float sc = ssh[0], sh = ssh[1];
  int qt = q0 + tid*8;
  int y = qt / W_;
  int x0i = qt - y*W_;
  float py = srcy(y);
  int y0 = (int)py; y0 = y0 > 12 ? 12 : y0;
  float wy = py - (float)y0;
  const float* r0 = cs + (y0 - Y0)*14;
  const float* r1 = r0 + 14;
  float vd[8], vc[8];
  #pragma unroll
  for (int u = 0; u < 8; ++u) {
    int x = x0i + u;
    float px = ((float)x + 0.5f) * (14.f/(float)W_) - 0.5f;
    px = fminf(fmaxf(px, 0.f), 13.f);
    int xq = (int)px; xq = xq > 12 ? 12 : xq;
    float wx = px - (float)xq;
    float v = (r0[xq]*(1.f-wx) + r0[xq+1]*wx) * (1.f-wy)
            + (r1[xq]*(1.f-wx) + r1[xq+1]*wx) * wy;
    vc[u] = v;
    vd[u] = fmaxf(v*sc + sh, 0.001f);
  }
  size_t base = (size_t)m * H_ * W_ + qt;
  float* od = out + base;
  float* oc = out + (size_t)M_*H_*W_ + base;
  f32x4 d0 = (f32x4){vd[0], vd[1], vd[2], vd[3]};
  f32x4 d1 = (f32x4){vd[4], vd[5], vd[6], vd[7]};
  f32x4 c0 = (f32x4){vc[0], vc[1], vc[2], vc[3]};
  f32x4 c1 = (f32x4){vc[4], vc[5], vc[6], vc[7]};
  __builtin_nontemporal_store(d0, (f32x4*)(od));
  __builtin_nontemporal_store(d1, (f32x4*)(od + 4));
  __builtin_nontemporal_store(c0, (f32x4*)(oc));
  __builtin_nontemporal_store(c1, (f32x4*)(oc + 4));
}

extern "C" void kernel_launch(void* const* d_in, const int* in_sizes, int n_in,
                              void* d_out, int out_size, void* d_ws, size_t ws_size,
                              hipStream_t stream) {
  const float* fmap  = (const float*)d_in[2];
  const float* boxes = (const float*)d_in[8];
  const int* labels  = (const int*)d_in[9];
  const float* w_s  = (const float*)d_in[10];
  const float* b_s  = (const float*)d_in[11];
  const float* w_fc = (const float*)d_in[12];
  const float* b_fc = (const float*)d_in[13];
  const float* w_c1 = (const float*)d_in[14];
  const float* b_c1 = (const float*)d_in[15];
  const float* w_c2 = (const float*)d_in[16];
  const float* b_c2 = (const float*)d_in[17];
  float* ws = (float*)d_ws;
  float* out = (float*)d_out;

  hipLaunchKernelGGL(prep_xb_kernel, dim3(XB_BLOCKS + PREP_BLOCKS), dim3(256), 0, stream,
                     fmap, boxes, w_s, b_s, w_fc, b_fc, w_c1, b_c1, w_c2, b_c2, ws);
  hipLaunchKernelGGL(gemm_kernel, dim3(M_*4), dim3(256), 0, stream,
                     labels, ws);
  hipLaunchKernelGGL(resize_kernel, dim3(M_*150), dim3(256), 0, stream,
                     labels, ws, out);
}

// Round 7
// 375.659 us; speedup vs baseline: 1.1154x; 1.0181x over previous
//
#include <hip/hip_runtime.h>

// RegressionInstancesModule on gfx950.
// R10 = resubmit of R8/R9 (exact R5 revert, measured 376.8us) after two
// consecutive infrastructure failures ("MI355X container failed twice") —
// no code change. History: R6 (full-N GEMM, 128-block grid) +42us (half CUs
// idle, VGPR cap); R7 (convc2/fc folded into resize) +5.6us (84 MB redundant
// Xh restaging). Structure: prep+xb merged; 256-block 128x128 bf16-MFMA GEMM
// with K-step register prefetch; convc2+fc kernel; resize with NT stores.
// Remaining window cost dominated by harness poison fill (~95us @83% HBM
// peak) + reset memsets, not controllable from kernel code.

typedef unsigned short bfu;
typedef __attribute__((ext_vector_type(8))) short bf16x8;
typedef __attribute__((ext_vector_type(4))) float f32x4;

__device__ __forceinline__ float bf2f(bfu u) {
  union { unsigned int i; float f; } v;
  v.i = ((unsigned int)u) << 16;
  return v.f;
}
__device__ __forceinline__ bfu f2bf(float f) {
  union { float f; unsigned int i; } v;
  v.f = f;
  unsigned int u = v.i;
  u = (u + 0x7fffu + ((u >> 16) & 1u)) >> 16;
  return (bfu)u;
}

#define B_  4
#define N_  16
#define M_  64
#define H_  480
#define W_  640
#define HF  120
#define WF  160
#define C_  128
#define R_  14
#define PIX 196
#define NE  13
#define KK  1152   // 9*128

// workspace layout (float offsets); total ~2.68M floats (10.7 MB)
#define WS_XB    0                         // bf16 Xb[64][196][128]
#define WS_XH    802816                    // bf16 Xh[64][196][64]
#define WS_C     1204224                   // f32 c[64][196]
#define WS_GAP   1216768                   // f32 gap[64][128] (sums; zeroed)
#define WS_SCALE 1224960                   // f32 [64]
#define WS_SHIFT 1225024                   // f32 [64]
#define WS_WF    1225088                   // bf16 WF[13][192][1152], k=kidx*128+ic
#define WS_BIASF 2662784                   // f32 [13][192]
#define WS_W2    2665280                   // f32 [13][576], idx=kidx*64+ic
#define WS_B2    2672768                   // f32 [13] (pad 16)
#define WS_WFC   2672784                   // f32 [13][2][128]
#define WS_BFC   2676112                   // f32 [13][2] (pad 32)

#define XB_BLOCKS 256   // 4 blocks per instance, 32 channels each
#define PREP_BLOCKS 1024

// ---------------- merged: ROI-align staging (blocks 0..255) + weight prep ----------------
__global__ __launch_bounds__(256) void prep_xb_kernel(
    const float* __restrict__ fmap, const float* __restrict__ boxes,
    const float* __restrict__ w_s, const float* __restrict__ b_s,
    const float* __restrict__ w_fc, const float* __restrict__ b_fc,
    const float* __restrict__ w_c1, const float* __restrict__ b_c1,
    const float* __restrict__ w_c2, const float* __restrict__ b_c2,
    float* __restrict__ ws)
{
  int tid = threadIdx.x;
  if (blockIdx.x < XB_BLOCKS) {
    // ---- ROI staging: block = (m, channel-quarter); lane = pixel ----
    __shared__ int iy0[R_], ix0[R_];
    __shared__ float swy[R_], swx[R_];
    __shared__ unsigned int lt[PIX][17];   // packed bf16 pairs, padded stride
    int m  = blockIdx.x >> 2;
    int cb = (blockIdx.x & 3) * 32;        // channel base (32 channels)
    if (tid < 2*R_) {
      int r = tid % R_;
      bool isY = tid < R_;
      float b0 = boxes[m*4 + (isY ? 0 : 1)];
      float b2 = boxes[m*4 + (isY ? 2 : 3)];
      float lo = 0.6f * b0;
      float hi = lo + 0.1f + 0.3f * b2;
      float t = ((float)r + 0.5f) / (float)R_;
      float dim = isY ? (float)(HF-1) : (float)(WF-1);
      float s = (lo + (hi - lo) * t) * dim;
      int maxi = isY ? (HF-2) : (WF-2);
      int i0 = (int)floorf(s);
      i0 = i0 < 0 ? 0 : (i0 > maxi ? maxi : i0);
      float w = s - (float)i0;
      w = w < 0.f ? 0.f : (w > 1.f ? 1.f : w);
      if (isY) { iy0[r] = i0; swy[r] = w; } else { ix0[r] = i0; swx[r] = w; }
    }
    __syncthreads();
    int bi = m / N_;
    const float* fb = fmap + ((size_t)bi * C_ + cb) * HF * WF;
    if (tid < PIX) {
      int ry = tid / 14, rx = tid - (tid/14)*14;
      int y0 = iy0[ry], x0 = ix0[rx];
      float wy = swy[ry], wx = swx[rx];
      float w00 = (1.f-wy)*(1.f-wx), w01 = (1.f-wy)*wx;
      float w10 = wy*(1.f-wx),       w11 = wy*wx;
      const float* fp = fb + (size_t)y0*WF + x0;
      #pragma unroll 4
      for (int c2 = 0; c2 < 16; ++c2) {
        const float* f0 = fp + (size_t)(2*c2)*HF*WF;
        const float* f1 = f0 + (size_t)HF*WF;
        float v0 = f0[0]*w00 + f0[1]*w01 + f0[WF]*w10 + f0[WF+1]*w11;
        float v1 = f1[0]*w00 + f1[1]*w01 + f1[WF]*w10 + f1[WF+1]*w11;
        lt[tid][c2] = (unsigned int)f2bf(v0) | ((unsigned int)f2bf(v1) << 16);
      }
    }
    __syncthreads();
    // flush: ic-contiguous bf16 layout Xb[m][p][ic], coalesced 64B per pixel
    unsigned int* xbw = (unsigned int*)(ws + WS_XB);
    for (int idx = tid; idx < PIX*16; idx += 256) {
      int p = idx >> 4, c2 = idx & 15;
      xbw[((size_t)m*PIX + p)*64 + (cb >> 1) + c2] = lt[p][c2];
    }
    return;
  }

  // ---- weight prep (blocks 256..1279), grid-stride ----
  const int P0 = NE*192*KK;     // WF bf16
  const int P1 = NE*192;        // biasf
  const int P2 = NE*576;        // w2
  const int P3 = NE;            // b2
  const int P4 = NE*256;        // wfc
  const int P5 = NE*2;          // bfc
  const int P6 = M_*C_;         // gap zero
  int total = P0+P1+P2+P3+P4+P5+P6;
  bfu* wf = (bfu*)(ws + WS_WF);
  for (int idx = (blockIdx.x - XB_BLOCKS)*256 + tid; idx < total;
       idx += PREP_BLOCKS*256) {
    int d = idx;
    if (d < P0) {
      int e = d / (192*KK);
      int r = d - e*(192*KK);
      int oc = r / KK;
      int k  = r - oc*KK;
      int kidx = k >> 7, ic = k & 127;
      float v = (oc < 128) ? w_s[((e*128 + oc)*128 + ic)*9 + kidx]
                           : w_c1[((e*64 + (oc-128))*128 + ic)*9 + kidx];
      wf[d] = f2bf(v);
      continue;
    }
    d -= P0;
    if (d < P1) {
      int e = d / 192, oc = d - e*192;
      ws[WS_BIASF + d] = (oc < 128) ? b_s[e*128 + oc] : b_c1[e*64 + oc - 128];
      continue;
    }
    d -= P1;
    if (d < P2) {
      int e = d / 576, k = d - e*576;
      int kidx = k >> 6, ic = k & 63;
      ws[WS_W2 + d] = w_c2[(e*64 + ic)*9 + kidx];
      continue;
    }
    d -= P2;
    if (d < P3) { ws[WS_B2 + d] = b_c2[d]; continue; }
    d -= P3;
    if (d < P4) { ws[WS_WFC + d] = w_fc[d]; continue; }
    d -= P4;
    if (d < P5) { ws[WS_BFC + d] = b_fc[d]; continue; }
    d -= P5;
    ws[WS_GAP + d] = 0.f;
  }
}

// ---------------- fused GEMM: [192oc x 208pix] = WF x im2col(Xb) ----------------
// block: 256 thr = 4 waves; tile 128M x 128N; grid = 64 inst * 2 mb * 2 nb.
// K-loop: 36 steps of 32; next-step A/B prefetched into regs so global L2
// latency overlaps ds_read+MFMA of the current step.
__global__ __launch_bounds__(256) void gemm_kernel(
    const int* __restrict__ labels, float* __restrict__ ws)
{
  __shared__ bfu lA[128*32];
  __shared__ bfu lB[128*32];
  const bfu* Xb = (const bfu*)(ws + WS_XB);
  const bfu* WFp = (const bfu*)(ws + WS_WF);
  const float* biasf = ws + WS_BIASF;
  float* gap = ws + WS_GAP;
  bfu* Xh = (bfu*)(ws + WS_XH);

  int bx = blockIdx.x;
  int m  = bx >> 2;
  int mb = (bx >> 1) & 1;
  int nb = bx & 1;
  int e = labels[m];
  int tid = threadIdx.x;
  int wave = tid >> 6, lane = tid & 63;
  int wm = wave >> 1, wn = wave & 1;
  int l15 = lane & 15, q = lane >> 4;

  int row0 = tid >> 2, row1 = row0 + 64;
  int kc = tid & 3;
  int loff0 = row0*32 + (kc ^ ((row0 >> 1) & 3))*8;
  int loff1 = row1*32 + (kc ^ ((row1 >> 1) & 3))*8;
  int g0 = mb*128 + row0, g1 = mb*128 + row1;
  bool av0 = g0 < 192, av1 = g1 < 192;
  const bfu* wfe = WFp + (size_t)e*192*KK;
  const bfu* wr0 = wfe + (size_t)g0*KK + kc*8;
  const bfu* wr1 = wfe + (size_t)g1*KK + kc*8;
  int pg0 = nb*128 + row0, pg1 = nb*128 + row1;
  int py0 = pg0 / 14, px0 = pg0 - (pg0/14)*14;
  int py1 = pg1 / 14, px1 = pg1 - (pg1/14)*14;
  bool pv0 = pg0 < PIX, pv1 = pg1 < PIX;
  const bfu* xbm = Xb + (size_t)m*PIX*128;

  f32x4 acc[4][4];
  #pragma unroll
  for (int i = 0; i < 4; ++i)
    #pragma unroll
    for (int j = 0; j < 4; ++j)
      acc[i][j] = (f32x4){0.f, 0.f, 0.f, 0.f};

  const uint4 z4 = make_uint4(0,0,0,0);
  uint4 na0, na1, nb0, nb1;
  auto issue = [&](int s, uint4& A0, uint4& A1, uint4& B0, uint4& B1) {
    int kidx = s >> 2, icc = s & 3;
    int t3 = kidx / 3;
    int dy = t3 - 1, dx = (kidx - t3*3) - 1;
    A0 = av0 ? *(const uint4*)(wr0 + s*32) : z4;
    A1 = av1 ? *(const uint4*)(wr1 + s*32) : z4;
    int ys0 = py0 + dy, xs0 = px0 + dx;
    int ys1 = py1 + dy, xs1 = px1 + dx;
    bool v0 = pv0 && (unsigned)ys0 < 14u && (unsigned)xs0 < 14u;
    bool v1 = pv1 && (unsigned)ys1 < 14u && (unsigned)xs1 < 14u;
    B0 = v0 ? *(const uint4*)(xbm + (size_t)(ys0*14+xs0)*128 + icc*32 + kc*8) : z4;
    B1 = v1 ? *(const uint4*)(xbm + (size_t)(ys1*14+xs1)*128 + icc*32 + kc*8) : z4;
  };
  issue(0, na0, na1, nb0, nb1);

  for (int s = 0; s < 36; ++s) {
    __syncthreads();
    *(uint4*)&lA[loff0] = na0;
    *(uint4*)&lA[loff1] = na1;
    *(uint4*)&lB[loff0] = nb0;
    *(uint4*)&lB[loff1] = nb1;
    __syncthreads();
    if (s < 35) issue(s+1, na0, na1, nb0, nb1);
    bf16x8 af[4], bfr[4];
    #pragma unroll
    for (int i = 0; i < 4; ++i) {
      int r = wm*64 + i*16 + l15;
      af[i] = *(const bf16x8*)&lA[r*32 + (q ^ ((r >> 1) & 3))*8];
    }
    #pragma unroll
    for (int j = 0; j < 4; ++j) {
      int r = wn*64 + j*16 + l15;
      bfr[j] = *(const bf16x8*)&lB[r*32 + (q ^ ((r >> 1) & 3))*8];
    }
    #pragma unroll
    for (int i = 0; i < 4; ++i)
      #pragma unroll
      for (int j = 0; j < 4; ++j)
        acc[i][j] = __builtin_amdgcn_mfma_f32_16x16x32_bf16(af[i], bfr[j], acc[i][j], 0, 0, 0);
  }

  if (mb == 0) {
    #pragma unroll
    for (int i = 0; i < 4; ++i) {
      int ocb = wm*64 + i*16 + q*4;
      f32x4 bv = *(const f32x4*)&biasf[e*192 + ocb];
      #pragma unroll
      for (int r = 0; r < 4; ++r) {
        float sum = 0.f;
        #pragma unroll
        for (int j = 0; j < 4; ++j) {
          int p = nb*128 + wn*64 + j*16 + l15;
          float v = acc[i][j][r] + bv[r];
          v = v > 0.f ? v : 0.f;
          if (p < PIX) sum += v;
        }
        sum += __shfl_xor(sum, 1);
        sum += __shfl_xor(sum, 2);
        sum += __shfl_xor(sum, 4);
        sum += __shfl_xor(sum, 8);
        if (l15 == 0) atomicAdd(&gap[m*C_ + ocb + r], sum);
      }
    }
  } else if (wm == 0) {
    #pragma unroll
    for (int i = 0; i < 4; ++i) {
      int icb = i*16 + q*4;
      f32x4 bv = *(const f32x4*)&biasf[e*192 + 128 + icb];
      #pragma unroll
      for (int j = 0; j < 4; ++j) {
        int p = nb*128 + wn*64 + j*16 + l15;
        if (p < PIX) {
          ushort4 pk;
          float v0 = acc[i][j][0] + bv[0]; v0 = v0 > 0.f ? v0 : 0.f;
          float v1 = acc[i][j][1] + bv[1]; v1 = v1 > 0.f ? v1 : 0.f;
          float v2 = acc[i][j][2] + bv[2]; v2 = v2 > 0.f ? v2 : 0.f;
          float v3 = acc[i][j][3] + bv[3]; v3 = v3 > 0.f ? v3 : 0.f;
          pk.x = f2bf(v0); pk.y = f2bf(v1); pk.z = f2bf(v2); pk.w = f2bf(v3);
          *(ushort4*)&Xh[((size_t)m*PIX + p)*64 + icb] = pk;
        }
      }
    }
  }
}

// ---------------- conv_c2 (3x3, 64ch -> 1) + fused FC (scale/shift) ----------------
__global__ __launch_bounds__(256) void convc2_kernel(
    const int* __restrict__ labels, float* __restrict__ ws,
    float* __restrict__ out)
{
  __shared__ bfu xh[PIX*64];
  __shared__ float w2l[576];
  int m = blockIdx.x;
  int e = labels[m];
  int tid = threadIdx.x;
  int wave = tid >> 6, lane = tid & 63;

  // FC: wave 0 -> scale, wave 1 -> shift (gap sums are complete after gemm)
  if (wave < 2) {
    const float* g  = ws + WS_GAP + m*C_;
    const float* wv = ws + WS_WFC + (e*2 + wave)*C_;
    float s = g[lane]*wv[lane] + g[lane+64]*wv[lane+64];
    #pragma unroll
    for (int d = 32; d; d >>= 1) s += __shfl_xor(s, d);
    if (lane == 0) {
      s = ws[WS_BFC + e*2 + wave] + s * (1.f/(float)PIX);
      size_t base = (size_t)2 * M_ * H_ * W_;
      if (wave == 0) { ws[WS_SCALE + m] = s; out[base + m] = s; }
      else           { ws[WS_SHIFT + m] = s; out[base + M_ + m] = s; }
    }
  }

  const bfu* Xh = (const bfu*)(ws + WS_XH) + (size_t)m*PIX*64;
  for (int i = tid; i < PIX*64/8; i += 256)
    *(uint4*)&xh[i*8] = *(const uint4*)&Xh[i*8];
  for (int i = tid; i < 576; i += 256)
    w2l[i] = ws[WS_W2 + e*576 + i];
  __syncthreads();
  if (tid < PIX) {
    int y = tid / 14, x = tid - (tid/14)*14;
    float acc = 0.f;
    #pragma unroll
    for (int kidx = 0; kidx < 9; ++kidx) {
      int ys = y + kidx/3 - 1, xs = x + (kidx - (kidx/3)*3) - 1;
      if ((unsigned)ys < 14u && (unsigned)xs < 14u) {
        const bfu* xr = xh + (ys*14 + xs)*64;
        const float* wr = w2l + kidx*64;
        #pragma unroll
        for (int cc = 0; cc < 8; ++cc) {
          bf16x8 xv = *(const bf16x8*)&xr[cc*8];
          f32x4 wa = *(const f32x4*)&wr[cc*8];
          f32x4 wb = *(const f32x4*)&wr[cc*8 + 4];
          acc += bf2f((bfu)xv[0])*wa[0] + bf2f((bfu)xv[1])*wa[1]
               + bf2f((bfu)xv[2])*wa[2] + bf2f((bfu)xv[3])*wa[3]
               + bf2f((bfu)xv[4])*wb[0] + bf2f((bfu)xv[5])*wb[1]
               + bf2f((bfu)xv[6])*wb[2] + bf2f((bfu)xv[7])*wb[3];
        }
      }
    }
    ws[WS_C + m*PIX + tid] = acc + ws[WS_B2 + e];
  }
}

// ---------------- bilinear resize 14x14 -> 480x640 + affine ----------------
__global__ __launch_bounds__(256) void resize_kernel(
    const float* __restrict__ ws_c, const float* __restrict__ ws_scale,
    const float* __restrict__ ws_shift, float* __restrict__ out)
{
  __shared__ float cs[PIX];
  int bx = blockIdx.x;
  int m = bx / 150;
  int chunk = bx % 150;
  int tid = threadIdx.x;
  if (tid < PIX) cs[tid] = ws_c[m*PIX + tid];
  __syncthreads();
  float sc = ws_scale[m], sh = ws_shift[m];
  int q0 = chunk*2048 + tid*8;
  int y = q0 / W_;
  int x0i = q0 - y*W_;
  float py = ((float)y + 0.5f) * (14.f/(float)H_) - 0.5f;
  py = fminf(fmaxf(py, 0.f), 13.f);
  int y0 = (int)py; y0 = y0 > 12 ? 12 : y0;
  float wy = py - (float)y0;
  const float* r0 = cs + y0*R_;
  const float* r1 = r0 + R_;
  float vd[8], vc[8];
  #pragma unroll
  for (int u = 0; u < 8; ++u) {
    int x = x0i + u;
    float px = ((float)x + 0.5f) * (14.f/(float)W_) - 0.5f;
    px = fminf(fmaxf(px, 0.f), 13.f);
    int xq = (int)px; xq = xq > 12 ? 12 : xq;
    float wx = px - (float)xq;
    float v = (r0[xq]*(1.f-wx) + r0[xq+1]*wx) * (1.f-wy)
            + (r1[xq]*(1.f-wx) + r1[xq+1]*wx) * wy;
    vc[u] = v;
    vd[u] = fmaxf(v*sc + sh, 0.001f);
  }
  size_t base = (size_t)m * H_ * W_ + q0;
  float* od = out + base;
  float* oc = out + (size_t)M_*H_*W_ + base;
  f32x4 d0 = (f32x4){vd[0], vd[1], vd[2], vd[3]};
  f32x4 d1 = (f32x4){vd[4], vd[5], vd[6], vd[7]};
  f32x4 c0 = (f32x4){vc[0], vc[1], vc[2], vc[3]};
  f32x4 c1 = (f32x4){vc[4], vc[5], vc[6], vc[7]};
  __builtin_nontemporal_store(d0, (f32x4*)(od));
  __builtin_nontemporal_store(d1, (f32x4*)(od + 4));
  __builtin_nontemporal_store(c0, (f32x4*)(oc));
  __builtin_nontemporal_store(c1, (f32x4*)(oc + 4));
}

extern "C" void kernel_launch(void* const* d_in, const int* in_sizes, int n_in,
                              void* d_out, int out_size, void* d_ws, size_t ws_size,
                              hipStream_t stream) {
  const float* fmap  = (const float*)d_in[2];
  const float* boxes = (const float*)d_in[8];
  const int* labels  = (const int*)d_in[9];
  const float* w_s  = (const float*)d_in[10];
  const float* b_s  = (const float*)d_in[11];
  const float* w_fc = (const float*)d_in[12];
  const float* b_fc = (const float*)d_in[13];
  const float* w_c1 = (const float*)d_in[14];
  const float* b_c1 = (const float*)d_in[15];
  const float* w_c2 = (const float*)d_in[16];
  const float* b_c2 = (const float*)d_in[17];
  float* ws = (float*)d_ws;
  float* out = (float*)d_out;

  hipLaunchKernelGGL(prep_xb_kernel, dim3(XB_BLOCKS + PREP_BLOCKS), dim3(256), 0, stream,
                     fmap, boxes, w_s, b_s, w_fc, b_fc, w_c1, b_c1, w_c2, b_c2, ws);
  hipLaunchKernelGGL(gemm_kernel, dim3(M_*4), dim3(256), 0, stream,
                     labels, ws);
  hipLaunchKernelGGL(convc2_kernel, dim3(M_), dim3(256), 0, stream,
                     labels, ws, out);
  hipLaunchKernelGGL(resize_kernel, dim3(M_*150), dim3(256), 0, stream,
                     ws + WS_C, ws + WS_SCALE, ws + WS_SHIFT, out);
}